// Round 4
// baseline (2559.721 us; speedup 1.0000x reference)
//
#include <hip/hip_runtime.h>

// Persistent-CG: K (64 MiB) held in VGPRs (128 regs/thread) across all 47 iters in
// ONE cooperative kernel; 2 grid barriers/iter.
// R3 post-mortem: 2322us, VALUBusy 12.5% -> ~2ms still in 96 phases (~20us ea).
// FETCH/WRITE unchanged vs R2 => traffic was never the issue; the tree barrier's
// serialized fetch_adds (16 RMWs/line x ~0.7us L3 round-trip, leaf then root) were.
// R4: RMW-free flag barrier. Arrival = one relaxed agent store to own flag word;
// wait = 256 threads poll their own flag (parallel sc1 loads, s_sleep backoff);
// __syncthreads is the join; one release fence before arrive, one acquire after.

#define NN   4096
#define TT   17
#define PP   16
#define NTOT (NN*TT)          // 69632
#define NIT  47
#define NBLK 256              // 1 block/CU (LDS ~143 KB), cooperative co-residency
#define NTHR 512              // 8 waves; __launch_bounds__(512,2) -> <=256 VGPR
#define EPB  (NTOT/NBLK)      // 272 elems/block for init+update

// ws float offsets
#define O_SSQ  0                    // [16][64] setup ssq partials
#define O_SLOT (O_SSQ + 16*64)      // [256][64] per-iter dot-product slots
#define O_BAR  (O_SLOT + NBLK*64)   // 256 monotonic per-block flag words
#define O_R    (O_BAR + 576)
#define O_P    (O_R + NTOT)
#define O_S    (O_P + NTOT)
#define O_X    (O_S + NTOT)
#define O_W0   (O_X + NTOT)         // 4 k-split partials of K@r

__global__ void k_bzero(float* __restrict__ ws) {
    if (threadIdx.x < 576) ((unsigned*)(ws + O_BAR))[threadIdx.x] = 0u;
}

// RMW-free monotonic flag barrier. Block b arrives by storing phase+1 to its own
// word (no atomic contention); threads 0..255 poll flags[t] at agent scope (sc1
// reads from the coherence point -- per-XCD L2 can't go stale on the poll path);
// __syncthreads joins the block when all 256 flags reached the target. Exactly one
// release fence (wbl2) per block before arrival and one acquire fence (inv) after
// the join, same as the R3 scheme the absmax validated.
__device__ __forceinline__ void gridbar(unsigned* flags, int phase, int b) {
    const unsigned target = (unsigned)(phase + 1);
    __syncthreads();                     // all waves' phase work complete
    if (threadIdx.x == 0) {
        __builtin_amdgcn_fence(__ATOMIC_RELEASE, "agent");
        __hip_atomic_store(&flags[b], target,
                           __ATOMIC_RELAXED, __HIP_MEMORY_SCOPE_AGENT);
    }
    if (threadIdx.x < NBLK) {
        while (__hip_atomic_load(&flags[threadIdx.x], __ATOMIC_RELAXED,
                                 __HIP_MEMORY_SCOPE_AGENT) < target)
            __builtin_amdgcn_s_sleep(1);
    }
    __syncthreads();                     // join: all 256 flags at target
    if (threadIdx.x == 0)
        __builtin_amdgcn_fence(__ATOMIC_ACQUIRE, "agent");  // inv L1+XCD-L2
    __syncthreads();                     // inv precedes all post-barrier reads
}

__global__ __launch_bounds__(NTHR, 2)
void k_cg(const float* __restrict__ Km, const float* __restrict__ yv,
          const float* __restrict__ Zm, const float* __restrict__ noise,
          float* __restrict__ out, float* __restrict__ ws) {
    __shared__ __align__(16) float rl[TT*1024];  // r k-slice [c][1024], 68 KB
    __shared__ float4 p2a[8*TT*17];              // wave partials rows 0-3 (pad 17)
    __shared__ float4 p2b[8*TT*17];              // rows 4-7; stride 17 -> no bank dup
    __shared__ float sm[8][64];
    __shared__ float s_scale[TT], s_rhs[TT], s_al[TT], s_be[TT], s_ap[TT], s_gp[TT];
    __shared__ float redd[TT], redg[TT];

    const int t = threadIdx.x, b = blockIdx.x;
    const int lane = t & 63, w = t >> 6;         // 8 waves
    const int rb = b >> 2, kb = b & 3;           // 64 row-blocks x 4 k-blocks
    const int row0 = rb*64 + w*8;                // 8 rows per wave
    unsigned* bar = (unsigned*)(ws + O_BAR);
    float* r_ = ws + O_R;
    const float s2 = noise[0]*noise[0];
    int ph = 0;                                  // barrier phase counter

    // ---- one-time: K tile -> registers. lane owns k = kb*1024 + g*256 + lane*4 ----
    float4 kreg[8][4];                            // 128 VGPRs
    {
        const float* Kb = Km + (size_t)row0*NN + kb*1024 + lane*4;
        #pragma unroll
        for (int rr = 0; rr < 8; ++rr)
            #pragma unroll
            for (int g = 0; g < 4; ++g)
                kreg[rr][g] = *(const float4*)(Kb + (size_t)rr*NN + g*256);
    }

    // ---- setup: per-column sum-of-squares partials (blocks 0..15) ----
    if (t < TT) redd[t] = 0.f;
    __syncthreads();
    if (b < 16 && t < 256) {
        int n = b*256 + t;
        float yy = yv[n];
        atomicAdd(&redd[0], yy*yy);
        #pragma unroll
        for (int j = 0; j < PP; ++j) { float v = Zm[n*PP + j]; atomicAdd(&redd[j+1], v*v); }
    }
    __syncthreads();
    if (b < 16 && t < TT) ws[O_SSQ + b*64 + t] = redd[t];
    gridbar(bar, ph++, b);

    // ---- setup: scale/rhs (replicated per block), init r/p/s/x (272 elems) ----
    if (t < TT) {
        float s = 0.f;
        #pragma unroll
        for (int i = 0; i < 16; ++i) s += ws[O_SSQ + i*64 + t];
        float scale, rh;
        if (t == 0) {
            rh = sqrtf(s); if (rh < 1e-10f) rh = 1.f;
            scale = 1.f/rh;
        } else {
            float zn = sqrtf(s);
            float bn = zn/(zn + 1e-10f);
            rh = (bn < 1e-10f) ? 1.f : bn;
            scale = 1.f/((zn + 1e-10f)*rh);
        }
        s_scale[t] = scale; s_rhs[t] = rh;
    }
    __syncthreads();
    if (t < EPB) {
        int e = b*EPB + t, c = e >> 12, n = e & (NN-1);
        float raw = (c == 0) ? yv[n] : Zm[n*PP + (c-1)];
        r_[e] = raw * s_scale[c];
        ws[O_P + e] = 0.f; ws[O_S + e] = 0.f; ws[O_X + e] = 0.f;
    }
    gridbar(bar, ph++, b);

    // ---- 47 pipelined-CG iterations ----
    for (int it = 0; it < NIT; ++it) {
        // stage r[c][kb*1024..+1024) -> LDS; unrolled so all 9 loads are in flight
        {
            const float* rs = r_ + kb*1024;
            #pragma unroll
            for (int q = 0; q < 8; ++q) {
                int v = q*NTHR + t, c = v >> 8, k4 = (v & 255)*4;
                *(float4*)(rl + c*1024 + k4) = *(const float4*)(rs + c*NN + k4);
            }
            if (t < 256) {
                int v = 8*NTHR + t, c = v >> 8, k4 = (v & 255)*4;
                *(float4*)(rl + c*1024 + k4) = *(const float4*)(rs + c*NN + k4);
            }
        }
        if (t < TT) { redd[t] = 0.f; redg[t] = 0.f; }
        __syncthreads();

        // per column: 4x ds_read_b128 (stride-16B, conflict-free) + 128 fmac into
        // 8 row-accs; 2-stage butterfly (64->16 classes); stash to padded p2
        const float* rc0 = rl + lane*4;
        for (int c = 0; c < TT; ++c) {
            const float* rc = rc0 + c*1024;
            float acc[8];
            #pragma unroll
            for (int rr = 0; rr < 8; ++rr) acc[rr] = 0.f;
            #pragma unroll
            for (int g = 0; g < 4; ++g) {
                float4 rv = *(const float4*)(rc + g*256);
                #pragma unroll
                for (int rr = 0; rr < 8; ++rr)
                    acc[rr] += kreg[rr][g].x*rv.x + kreg[rr][g].y*rv.y
                             + kreg[rr][g].z*rv.z + kreg[rr][g].w*rv.w;
            }
            #pragma unroll
            for (int rr = 0; rr < 8; ++rr) {
                float v2 = acc[rr];
                v2 += __shfl_xor(v2, 32, 64);
                v2 += __shfl_xor(v2, 16, 64);
                acc[rr] = v2;
            }
            if (lane < 16) {
                p2a[(w*TT + c)*17 + lane] = make_float4(acc[0], acc[1], acc[2], acc[3]);
                p2b[(w*TT + c)*17 + lane] = make_float4(acc[4], acc[5], acc[6], acc[7]);
            }
        }
        __syncthreads();

        // finish: t<136 -> (w2,c2): sum 16 lane-classes, write w-partial, dot prods
        if (t < 8*TT) {
            int w2 = t / TT, c2 = t % TT;        // (w2*TT + c2) == t
            float4 sa = make_float4(0.f,0.f,0.f,0.f), sb = make_float4(0.f,0.f,0.f,0.f);
            #pragma unroll
            for (int i = 0; i < 16; ++i) {
                float4 u = p2a[t*17 + i];
                sa.x += u.x; sa.y += u.y; sa.z += u.z; sa.w += u.w;
                float4 v2 = p2b[t*17 + i];
                sb.x += v2.x; sb.y += v2.y; sb.z += v2.z; sb.w += v2.w;
            }
            int row = rb*64 + w2*8;
            float* wp = ws + O_W0 + kb*NTOT;
            *(float4*)(wp + c2*NN + row)     = sa;
            *(float4*)(wp + c2*NN + row + 4) = sb;
            float4 ra  = *(const float4*)(r_ + c2*NN + row);
            float4 rb4 = *(const float4*)(r_ + c2*NN + row + 4);
            float dp = ra.x*sa.x + ra.y*sa.y + ra.z*sa.z + ra.w*sa.w
                     + rb4.x*sb.x + rb4.y*sb.y + rb4.z*sb.z + rb4.w*sb.w;
            atomicAdd(&redd[c2], dp);
            if (kb == 0) {
                float gp = ra.x*ra.x + ra.y*ra.y + ra.z*ra.z + ra.w*ra.w
                         + rb4.x*rb4.x + rb4.y*rb4.y + rb4.z*rb4.z + rb4.w*rb4.w;
                atomicAdd(&redg[c2], gp);
            }
        }
        __syncthreads();
        if (t < TT) {
            ws[O_SLOT + b*64 + t]      = redd[t];
            ws[O_SLOT + b*64 + 32 + t] = (kb == 0) ? redg[t] : 0.f;
        }
        gridbar(bar, ph++, b);

        // phase B: alpha/beta replicated in every block (saves a 3rd barrier),
        // then this block's 272-elem p/s/x/r update
        {
            int seg = t >> 6, j = t & 63;
            float s = 0.f;
            if (j < TT || (j >= 32 && j < 32 + TT)) {
                #pragma unroll
                for (int i = 0; i < 32; ++i)
                    s += ws[O_SLOT + (seg*32 + i)*64 + j];
            }
            sm[seg][j] = s;
        }
        __syncthreads();
        if (t < TT) {
            float del = 0.f, gam = 0.f;
            #pragma unroll
            for (int g = 0; g < 8; ++g) { del += sm[g][t]; gam += sm[g][32 + t]; }
            float delta = del + s2*gam;           // r^T (K + s2 I) r
            float beta = 0.f, D = delta;
            if (it > 0) {
                float gp = s_gp[t];
                beta = (fabsf(gp) < 1e-30f) ? 0.f : gam/gp;
                float ap = s_ap[t];
                D = delta - ((fabsf(ap) < 1e-30f) ? 0.f : beta*gam/ap);
            }
            float alpha = (fabsf(D) < 1e-30f) ? 0.f : gam/D;
            s_al[t] = alpha; s_be[t] = beta; s_ap[t] = alpha; s_gp[t] = gam;
        }
        __syncthreads();
        if (t < EPB) {
            int e = b*EPB + t, c = e >> 12, n = e & (NN-1);
            float al = s_al[c], be = s_be[c];
            float rv = r_[e];
            float wv = ws[O_W0 + e] + ws[O_W0 + NTOT + e]
                     + ws[O_W0 + 2*NTOT + e] + ws[O_W0 + 3*NTOT + e] + s2*rv;
            float pn = rv + be*ws[O_P + e];
            float sn = wv + be*ws[O_S + e];
            float xn = ws[O_X + e] + al*pn;
            float rn = rv - al*sn;
            ws[O_P + e] = pn; ws[O_S + e] = sn; ws[O_X + e] = xn; r_[e] = rn;
            if (it == NIT-1) out[n*TT + c] = xn * s_rhs[c];
        }
        gridbar(bar, ph++, b);
    }
}

extern "C" void kernel_launch(void* const* d_in, const int* in_sizes, int n_in,
                              void* d_out, int out_size, void* d_ws, size_t ws_size,
                              hipStream_t stream) {
    const float* Km    = (const float*)d_in[0];
    const float* yv    = (const float*)d_in[1];
    const float* Zm    = (const float*)d_in[2];
    const float* noise = (const float*)d_in[3];
    float* out = (float*)d_out;
    float* ws  = (float*)d_ws;

    k_bzero<<<1, 576, 0, stream>>>(ws);
    void* args[] = {(void*)&Km, (void*)&yv, (void*)&Zm, (void*)&noise,
                    (void*)&out, (void*)&ws};
    hipLaunchCooperativeKernel((const void*)k_cg, dim3(NBLK), dim3(NTHR),
                               args, 0, stream);
}

// Round 6
// 1617.635 us; speedup vs baseline: 1.5824x; 1.5824x over previous
//
#include <hip/hip_runtime.h>

// Persistent-CG: K (64 MiB) in VGPRs (128/thread) across all 47 iters; 2 grid
// barriers/iter. R4 post-mortem: flag barrier with 65536 agent-scope pollers
// fetched 1.8MB/barrier from the coherence point (FETCH 122->296MB, dur worse).
// R2->R3 delta showed bulk wbl2/inv fences cost multi-us each.
// R5 (this scheme) failed to COMPILE: HIP float4 is a struct -> clang passes
// struct asm INPUTS indirectly, illegal for 'v'. R6 fix: ext_vector_type(4)
// operands for all inline asm (HK pattern). Semantics unchanged:
// fence-FREE explicit coherence. All cross-block data (r, W0, slots, ssq,
// flags) moves only via sc1 write-through stores + sc1 bypass loads, so
// XCD-L2 never holds them -> no staleness -> zero cache-maintenance fences.
// Barrier = store-only master-broadcast: blocks store own flag; block 0 polls
// flags with 255 threads and stores 8 'go' replicas; others poll go with ONE
// thread. Owner-private p/s/x stay on the cached path, never invalidated.

#define NN   4096
#define TT   17
#define PP   16
#define NTOT (NN*TT)          // 69632
#define NIT  47
#define NBLK 256              // 1 block/CU (LDS ~143 KB), cooperative co-residency
#define NTHR 512              // 8 waves
#define EPB  (NTOT/NBLK)      // 272 elems/block for init+update

// ws float offsets
#define O_SSQ  0                    // [16][64] setup ssq partials (sc1 path)
#define O_SLOT (O_SSQ + 16*64)      // [256][64] per-iter dot slots (sc1 path)
#define O_BAR  (O_SLOT + NBLK*64)   // flags[256] + go replicas at 256+32*i
#define O_R    (O_BAR + 576)        // r (sc1 path)
#define O_P    (O_R + NTOT)         // owner-private (cached path)
#define O_S    (O_P + NTOT)
#define O_X    (O_S + NTOT)
#define O_W0   (O_X + NTOT)         // 4 k-split partials of K@r (sc1 path)

#define AGENT __HIP_MEMORY_SCOPE_AGENT
#define RLX   __ATOMIC_RELAXED

typedef float f32x4 __attribute__((ext_vector_type(4)));   // asm-legal 128b vreg

__global__ void k_bzero(float* __restrict__ ws) {
    if (threadIdx.x < 576) ((unsigned*)(ws + O_BAR))[threadIdx.x] = 0u;
}

// Store-only monotonic grid barrier, no fences. Entry waitcnt drains each wave's
// sc1 stores (acks from L3) before syncthreads; flag store then happens-after all
// of the block's data is at the coherence point. Consumers read data with sc1
// loads (bypass stale caches), so no acquire-invalidate is needed either.
__device__ __forceinline__ void gridbar(unsigned* bar, int phase, int b) {
    const unsigned target = (unsigned)(phase + 1);
    asm volatile("s_waitcnt vmcnt(0)" ::: "memory");   // asm sc1 stores drained
    __syncthreads();
    if (b == 0) {
        if (threadIdx.x >= 1 && threadIdx.x < NBLK) {
            while (__hip_atomic_load(&bar[threadIdx.x], RLX, AGENT) < target)
                __builtin_amdgcn_s_sleep(1);
        }
        __syncthreads();                // all 255 flags reached target
        if (threadIdx.x < 8)
            __hip_atomic_store(&bar[256 + threadIdx.x*32], target, RLX, AGENT);
    } else {
        if (threadIdx.x == 0) {
            __hip_atomic_store(&bar[b], target, RLX, AGENT);
            while (__hip_atomic_load(&bar[256 + (b & 7)*32], RLX, AGENT) < target)
                __builtin_amdgcn_s_sleep(1);
        }
    }
    __syncthreads();
}

__global__ __launch_bounds__(NTHR, 2)
void k_cg(const float* __restrict__ Km, const float* __restrict__ yv,
          const float* __restrict__ Zm, const float* __restrict__ noise,
          float* __restrict__ out, float* __restrict__ ws) {
    __shared__ __align__(16) float rl[TT*1024];  // r k-slice [c][1024], 68 KB
    __shared__ float4 p2a[8*TT*17];              // wave partials rows 0-3 (pad 17)
    __shared__ float4 p2b[8*TT*17];              // rows 4-7
    __shared__ float sm[8][64];
    __shared__ float s_scale[TT], s_rhs[TT], s_al[TT], s_be[TT], s_ap[TT], s_gp[TT];
    __shared__ float redd[TT], redg[TT];

    const int t = threadIdx.x, b = blockIdx.x;
    const int lane = t & 63, w = t >> 6;         // 8 waves
    const int rb = b >> 2, kb = b & 3;           // 64 row-blocks x 4 k-blocks
    const int row0 = rb*64 + w*8;                // 8 rows per wave
    unsigned* bar = (unsigned*)(ws + O_BAR);
    float* r_ = ws + O_R;
    const float s2 = noise[0]*noise[0];
    int ph = 0;

    // ---- one-time: K tile -> registers (normal cached loads, read-only) ----
    float4 kreg[8][4];                            // 128 VGPRs
    {
        const float* Kb = Km + (size_t)row0*NN + kb*1024 + lane*4;
        #pragma unroll
        for (int rr = 0; rr < 8; ++rr)
            #pragma unroll
            for (int g = 0; g < 4; ++g)
                kreg[rr][g] = *(const float4*)(Kb + (size_t)rr*NN + g*256);
    }

    // ---- setup: per-column sum-of-squares partials (blocks 0..15) ----
    if (t < TT) redd[t] = 0.f;
    __syncthreads();
    if (b < 16 && t < 256) {
        int n = b*256 + t;
        float yy = yv[n];
        atomicAdd(&redd[0], yy*yy);
        #pragma unroll
        for (int j = 0; j < PP; ++j) { float v = Zm[n*PP + j]; atomicAdd(&redd[j+1], v*v); }
    }
    __syncthreads();
    if (b < 16 && t < TT)
        __hip_atomic_store(&ws[O_SSQ + b*64 + t], redd[t], RLX, AGENT);
    gridbar(bar, ph++, b);

    // ---- setup: scale/rhs (replicated), init r (sc1) / p,s,x (private) ----
    if (t < TT) {
        float s = 0.f;
        #pragma unroll
        for (int i = 0; i < 16; ++i)
            s += __hip_atomic_load(&ws[O_SSQ + i*64 + t], RLX, AGENT);
        float scale, rh;
        if (t == 0) {
            rh = sqrtf(s); if (rh < 1e-10f) rh = 1.f;
            scale = 1.f/rh;
        } else {
            float zn = sqrtf(s);
            float bn = zn/(zn + 1e-10f);
            rh = (bn < 1e-10f) ? 1.f : bn;
            scale = 1.f/((zn + 1e-10f)*rh);
        }
        s_scale[t] = scale; s_rhs[t] = rh;
    }
    __syncthreads();
    if (t < EPB) {
        int e = b*EPB + t, c = e >> 12, n = e & (NN-1);
        float raw = (c == 0) ? yv[n] : Zm[n*PP + (c-1)];
        __hip_atomic_store(&r_[e], raw * s_scale[c], RLX, AGENT);
        ws[O_P + e] = 0.f; ws[O_S + e] = 0.f; ws[O_X + e] = 0.f;
    }
    gridbar(bar, ph++, b);

    // ---- 47 pipelined-CG iterations ----
    for (int it = 0; it < NIT; ++it) {
        // stage r slice -> LDS via sc1 bypass loads (one bundle, one waitcnt)
        {
            const float* rs = r_ + kb*1024;
            f32x4 rv[8];
            const float* ap[8];
            #pragma unroll
            for (int q = 0; q < 8; ++q) {
                int v = q*NTHR + t, c = v >> 8, k4 = (v & 255) << 2;
                ap[q] = rs + c*NN + k4;
            }
            asm volatile(
                "global_load_dwordx4 %0, %8, off sc1\n\t"
                "global_load_dwordx4 %1, %9, off sc1\n\t"
                "global_load_dwordx4 %2, %10, off sc1\n\t"
                "global_load_dwordx4 %3, %11, off sc1\n\t"
                "global_load_dwordx4 %4, %12, off sc1\n\t"
                "global_load_dwordx4 %5, %13, off sc1\n\t"
                "global_load_dwordx4 %6, %14, off sc1\n\t"
                "global_load_dwordx4 %7, %15, off sc1\n\t"
                "s_waitcnt vmcnt(0)"
                : "=&v"(rv[0]), "=&v"(rv[1]), "=&v"(rv[2]), "=&v"(rv[3]),
                  "=&v"(rv[4]), "=&v"(rv[5]), "=&v"(rv[6]), "=&v"(rv[7])
                : "v"(ap[0]), "v"(ap[1]), "v"(ap[2]), "v"(ap[3]),
                  "v"(ap[4]), "v"(ap[5]), "v"(ap[6]), "v"(ap[7])
                : "memory");
            #pragma unroll
            for (int q = 0; q < 8; ++q) {
                int v = q*NTHR + t, c = v >> 8, k4 = (v & 255) << 2;
                *(f32x4*)(rl + c*1024 + k4) = rv[q];
            }
            if (t < 256) {
                int v = 8*NTHR + t, c = v >> 8, k4 = (v & 255) << 2;
                const float* a8 = rs + c*NN + k4;
                f32x4 r8;
                asm volatile(
                    "global_load_dwordx4 %0, %1, off sc1\n\t"
                    "s_waitcnt vmcnt(0)"
                    : "=&v"(r8) : "v"(a8) : "memory");
                *(f32x4*)(rl + c*1024 + k4) = r8;
            }
        }
        if (t < TT) { redd[t] = 0.f; redg[t] = 0.f; }
        __syncthreads();

        // per column: 4x ds_read_b128 + 128 fmac into 8 row-accs; 2-stage
        // butterfly (64->16 classes); stash to padded p2
        const float* rc0 = rl + lane*4;
        for (int c = 0; c < TT; ++c) {
            const float* rc = rc0 + c*1024;
            float acc[8];
            #pragma unroll
            for (int rr = 0; rr < 8; ++rr) acc[rr] = 0.f;
            #pragma unroll
            for (int g = 0; g < 4; ++g) {
                float4 rv = *(const float4*)(rc + g*256);
                #pragma unroll
                for (int rr = 0; rr < 8; ++rr)
                    acc[rr] += kreg[rr][g].x*rv.x + kreg[rr][g].y*rv.y
                             + kreg[rr][g].z*rv.z + kreg[rr][g].w*rv.w;
            }
            #pragma unroll
            for (int rr = 0; rr < 8; ++rr) {
                float v2 = acc[rr];
                v2 += __shfl_xor(v2, 32, 64);
                v2 += __shfl_xor(v2, 16, 64);
                acc[rr] = v2;
            }
            if (lane < 16) {
                p2a[(w*TT + c)*17 + lane] = make_float4(acc[0], acc[1], acc[2], acc[3]);
                p2b[(w*TT + c)*17 + lane] = make_float4(acc[4], acc[5], acc[6], acc[7]);
            }
        }
        __syncthreads();

        // finish: t<136 -> (w2,c2): sum 16 lane-classes, sc1-write W0 partial,
        // sc1-read r rows, local dots -> LDS atomics
        if (t < 8*TT) {
            int w2 = t / TT, c2 = t % TT;
            f32x4 sa = {0.f, 0.f, 0.f, 0.f}, sb = {0.f, 0.f, 0.f, 0.f};
            #pragma unroll
            for (int i = 0; i < 16; ++i) {
                float4 u = p2a[t*17 + i];
                sa.x += u.x; sa.y += u.y; sa.z += u.z; sa.w += u.w;
                float4 v2 = p2b[t*17 + i];
                sb.x += v2.x; sb.y += v2.y; sb.z += v2.z; sb.w += v2.w;
            }
            int row = rb*64 + w2*8;
            float* wp = ws + O_W0 + kb*NTOT;
            float* pa2 = wp + c2*NN + row;
            float* pb2 = pa2 + 4;
            asm volatile(
                "global_store_dwordx4 %2, %0, off sc1\n\t"
                "global_store_dwordx4 %3, %1, off sc1"
                :: "v"(sa), "v"(sb), "v"(pa2), "v"(pb2) : "memory");
            const float* qa = r_ + c2*NN + row;
            const float* qb = qa + 4;
            f32x4 ra, rb4;
            asm volatile(
                "global_load_dwordx4 %0, %2, off sc1\n\t"
                "global_load_dwordx4 %1, %3, off sc1\n\t"
                "s_waitcnt vmcnt(0)"
                : "=&v"(ra), "=&v"(rb4) : "v"(qa), "v"(qb) : "memory");
            float dp = ra.x*sa.x + ra.y*sa.y + ra.z*sa.z + ra.w*sa.w
                     + rb4.x*sb.x + rb4.y*sb.y + rb4.z*sb.z + rb4.w*sb.w;
            atomicAdd(&redd[c2], dp);
            if (kb == 0) {
                float gp = ra.x*ra.x + ra.y*ra.y + ra.z*ra.z + ra.w*ra.w
                         + rb4.x*rb4.x + rb4.y*rb4.y + rb4.z*rb4.z + rb4.w*rb4.w;
                atomicAdd(&redg[c2], gp);
            }
        }
        __syncthreads();
        if (t < TT) {
            __hip_atomic_store(&ws[O_SLOT + b*64 + t], redd[t], RLX, AGENT);
            __hip_atomic_store(&ws[O_SLOT + b*64 + 32 + t],
                               (kb == 0) ? redg[t] : 0.f, RLX, AGENT);
        }
        gridbar(bar, ph++, b);

        // phase B: alpha/beta replicated in every block, then own 272-elem update
        {
            int seg = t >> 6, j = t & 63;
            float s = 0.f;
            if (j < TT || (j >= 32 && j < 32 + TT)) {
                #pragma unroll
                for (int i = 0; i < 32; ++i)
                    s += __hip_atomic_load(&ws[O_SLOT + (seg*32 + i)*64 + j],
                                           RLX, AGENT);
            }
            sm[seg][j] = s;
        }
        __syncthreads();
        if (t < TT) {
            float del = 0.f, gam = 0.f;
            #pragma unroll
            for (int g = 0; g < 8; ++g) { del += sm[g][t]; gam += sm[g][32 + t]; }
            float delta = del + s2*gam;           // r^T (K + s2 I) r
            float beta = 0.f, D = delta;
            if (it > 0) {
                float gp = s_gp[t];
                beta = (fabsf(gp) < 1e-30f) ? 0.f : gam/gp;
                float ap = s_ap[t];
                D = delta - ((fabsf(ap) < 1e-30f) ? 0.f : beta*gam/ap);
            }
            float alpha = (fabsf(D) < 1e-30f) ? 0.f : gam/D;
            s_al[t] = alpha; s_be[t] = beta; s_ap[t] = alpha; s_gp[t] = gam;
        }
        __syncthreads();
        if (t < EPB) {
            int e = b*EPB + t, c = e >> 12, n = e & (NN-1);
            float al = s_al[c], be = s_be[c];
            float rv = __hip_atomic_load(&r_[e], RLX, AGENT);
            float w0 = __hip_atomic_load(&ws[O_W0 + e],          RLX, AGENT);
            float w1 = __hip_atomic_load(&ws[O_W0 + NTOT + e],   RLX, AGENT);
            float w2v = __hip_atomic_load(&ws[O_W0 + 2*NTOT + e], RLX, AGENT);
            float w3 = __hip_atomic_load(&ws[O_W0 + 3*NTOT + e], RLX, AGENT);
            float wv = w0 + w1 + w2v + w3 + s2*rv;
            float pn = rv + be*ws[O_P + e];       // p,s,x: owner-private cached
            float sn = wv + be*ws[O_S + e];
            float xn = ws[O_X + e] + al*pn;
            float rn = rv - al*sn;
            ws[O_P + e] = pn; ws[O_S + e] = sn; ws[O_X + e] = xn;
            __hip_atomic_store(&r_[e], rn, RLX, AGENT);
            if (it == NIT-1) out[n*TT + c] = xn * s_rhs[c];
        }
        gridbar(bar, ph++, b);
    }
}

extern "C" void kernel_launch(void* const* d_in, const int* in_sizes, int n_in,
                              void* d_out, int out_size, void* d_ws, size_t ws_size,
                              hipStream_t stream) {
    const float* Km    = (const float*)d_in[0];
    const float* yv    = (const float*)d_in[1];
    const float* Zm    = (const float*)d_in[2];
    const float* noise = (const float*)d_in[3];
    float* out = (float*)d_out;
    float* ws  = (float*)d_ws;

    k_bzero<<<1, 576, 0, stream>>>(ws);
    void* args[] = {(void*)&Km, (void*)&yv, (void*)&Zm, (void*)&noise,
                    (void*)&out, (void*)&ws};
    (void)hipLaunchCooperativeKernel((const void*)k_cg, dim3(NBLK), dim3(NTHR),
                                     args, 0, stream);
}